// Round 1
// baseline (613.158 us; speedup 1.0000x reference)
//
#include <hip/hip_runtime.h>
#include <cstdint>
#include <cstddef>

// Problem dims (fixed by setup_inputs): B=4, S=2048, I=4096, O=4096
#define DIM_M 8192   // B*S
#define DIM_N 4096   // O
#define DIM_K 4096   // I

#define BLK_M 128
#define BLK_N 128
#define BLK_K 32

typedef __bf16 bf16x8 __attribute__((ext_vector_type(8)));
typedef float floatx4 __attribute__((ext_vector_type(4)));

__device__ __constant__ float NF4_TAB[16] = {
    -1.0f, -0.6961928009986877f, -0.5250730514526367f, -0.39491748809814453f,
    -0.28444138169288635f, -0.18477343022823334f, -0.09105003625154495f, 0.0f,
    0.07958029955625534f, 0.16093020141124725f, 0.24611230194568634f,
    0.33791524171829224f, 0.44070982933044434f, 0.5626170039176941f,
    0.7229568362236023f, 1.0f};

// float -> bf16 bits, round-to-nearest-even (finite inputs only)
__device__ inline unsigned short f2bf(float f) {
    unsigned int u = __builtin_bit_cast(unsigned int, f);
    u += 0x7fffu + ((u >> 16) & 1u);
    return (unsigned short)(u >> 16);
}

// ---------------- x fp32 -> bf16 (8 elems/thread) ----------------
__global__ void xcv_kernel(const float* __restrict__ x, unsigned short* __restrict__ xb) {
    size_t base = ((size_t)blockIdx.x * blockDim.x + threadIdx.x) * 8;
    float4 a = *(const float4*)(x + base);
    float4 b = *(const float4*)(x + base + 4);
    unsigned short r[8];
    r[0] = f2bf(a.x); r[1] = f2bf(a.y); r[2] = f2bf(a.z); r[3] = f2bf(a.w);
    r[4] = f2bf(b.x); r[5] = f2bf(b.y); r[6] = f2bf(b.z); r[7] = f2bf(b.w);
    *(uint4*)(xb + base) = *(const uint4*)r;
}

// ---------------- NF4 + double-quant dequant -> bf16 w [N,K] ----------------
// w[o,i] = NF4[code[o,i]] * (am_code[blk]/255 * am_scale[blk/256] + am_off)
// blk = (o*K + i) / 64  (8 elems per thread stay within one 64-block)
__global__ void wdq_kernel(const int* __restrict__ codes,
                           const int* __restrict__ am_codes,
                           const float* __restrict__ am_scale,
                           const float* __restrict__ am_off,
                           unsigned short* __restrict__ wb) {
    __shared__ float nf4[16];
    if (threadIdx.x < 16) nf4[threadIdx.x] = NF4_TAB[threadIdx.x];
    __syncthreads();
    size_t base = ((size_t)blockIdx.x * blockDim.x + threadIdx.x) * 8;
    int blk = (int)(base >> 6);
    float absmax = (float)am_codes[blk] * (1.0f / 255.0f) * am_scale[blk >> 8] + am_off[0];
    int4 c0 = *(const int4*)(codes + base);
    int4 c1 = *(const int4*)(codes + base + 4);
    unsigned short r[8];
    r[0] = f2bf(nf4[c0.x & 15] * absmax);
    r[1] = f2bf(nf4[c0.y & 15] * absmax);
    r[2] = f2bf(nf4[c0.z & 15] * absmax);
    r[3] = f2bf(nf4[c0.w & 15] * absmax);
    r[4] = f2bf(nf4[c1.x & 15] * absmax);
    r[5] = f2bf(nf4[c1.y & 15] * absmax);
    r[6] = f2bf(nf4[c1.z & 15] * absmax);
    r[7] = f2bf(nf4[c1.w & 15] * absmax);
    *(uint4*)(wb + base) = *(const uint4*)r;
}

// ---------------- bf16 MFMA GEMM, B^T input, bias epilogue ----------------
__device__ inline void gld_lds16(const void* g, void* l) {
    __builtin_amdgcn_global_load_lds((__attribute__((address_space(1))) void*)g,
                                     (__attribute__((address_space(3))) void*)l,
                                     16, 0, 0);
}

__global__ __launch_bounds__(256) void gemm_bt(const unsigned short* __restrict__ A,
                                               const unsigned short* __restrict__ B,
                                               const float* __restrict__ bias,
                                               float* __restrict__ C,
                                               int M, int N, int K) {
    __shared__ __attribute__((aligned(16))) unsigned short lA[BLK_M * BLK_K];
    __shared__ __attribute__((aligned(16))) unsigned short lB[BLK_N * BLK_K];
    const int tid = threadIdx.x;
    const int wave = tid >> 6;
    const int lane = tid & 63;
    const int bm = blockIdx.y, bn = blockIdx.x;

    const int wm = (wave >> 1) * 64;  // wave m-offset within tile
    const int wn = (wave & 1) * 64;   // wave n-offset within tile

    // Staging: thread t copies 16B chunks at tile-linear elems t*8 and (t+256)*8.
    // LDS dest must be base + lane*16 in wave-lane order (global_load_lds rule):
    // lA[t*8] satisfies this (t = wave*64 + lane).
    const int er0 = (tid * 8) >> 5;   // row of first chunk (0..63)
    const int ec0 = (tid * 8) & 31;   // col of first chunk
    const unsigned short* gA = A + (size_t)(bm * BLK_M + er0) * K + ec0;
    const unsigned short* gB = B + (size_t)(bn * BLK_N + er0) * K + ec0;
    unsigned short* lA0 = &lA[tid * 8];
    unsigned short* lA1 = &lA[2048 + tid * 8];  // rows 64..127
    unsigned short* lB0 = &lB[tid * 8];
    unsigned short* lB1 = &lB[2048 + tid * 8];
    const size_t rstride = (size_t)64 * K;

    floatx4 acc[4][4];
#pragma unroll
    for (int i = 0; i < 4; ++i)
#pragma unroll
        for (int j = 0; j < 4; ++j)
#pragma unroll
            for (int r = 0; r < 4; ++r) acc[i][j][r] = 0.0f;

    // MFMA 16x16x32 A-operand layout: lane holds A[m = lane&15][k = (lane>>4)*8 + j]
    const int mrow = lane & 15;
    const int kq = (lane >> 4) * 8;

    for (int k0 = 0; k0 < K; k0 += BLK_K) {
        gld_lds16(gA, lA0);
        gld_lds16(gA + rstride, lA1);
        gld_lds16(gB, lB0);
        gld_lds16(gB + rstride, lB1);
        gA += BLK_K;
        gB += BLK_K;
        __syncthreads();  // drains vmcnt -> staging visible

        bf16x8 af[4], bfr[4];
#pragma unroll
        for (int i = 0; i < 4; ++i) {
            af[i] = *(const bf16x8*)&lA[(wm + i * 16 + mrow) * BLK_K + kq];
            bfr[i] = *(const bf16x8*)&lB[(wn + i * 16 + mrow) * BLK_K + kq];
        }
#pragma unroll
        for (int i = 0; i < 4; ++i)
#pragma unroll
            for (int j = 0; j < 4; ++j)
                acc[i][j] = __builtin_amdgcn_mfma_f32_16x16x32_bf16(af[i], bfr[j], acc[i][j], 0, 0, 0);
        __syncthreads();  // compute done before next stage overwrites
    }

    // Epilogue. C/D layout: col = lane&15, row = (lane>>4)*4 + reg
    const int r0 = (lane >> 4) * 4;
    const int col = lane & 15;
#pragma unroll
    for (int j = 0; j < 4; ++j) {
        int gn = bn * BLK_N + wn + j * 16 + col;
        float bv = bias[gn];
#pragma unroll
        for (int i = 0; i < 4; ++i) {
            int gm = bm * BLK_M + wm + i * 16 + r0;
            float* cp = C + (size_t)gm * N + gn;
            cp[0]              = acc[i][j][0] + bv;
            cp[(size_t)N]      = acc[i][j][1] + bv;
            cp[2 * (size_t)N]  = acc[i][j][2] + bv;
            cp[3 * (size_t)N]  = acc[i][j][3] + bv;
        }
    }
}

extern "C" void kernel_launch(void* const* d_in, const int* in_sizes, int n_in,
                              void* d_out, int out_size, void* d_ws, size_t ws_size,
                              hipStream_t stream) {
    const float* x        = (const float*)d_in[0];
    const int*   w_codes  = (const int*)d_in[1];
    const int*   am_codes = (const int*)d_in[2];
    const float* am_scale = (const float*)d_in[3];
    const float* am_off   = (const float*)d_in[4];
    const float* bias     = (const float*)d_in[5];
    float* out = (float*)d_out;

    const int M = DIM_M, N = DIM_N, K = DIM_K;

    // workspace: xb (M*K bf16 = 64 MB) | wb (N*K bf16 = 32 MB)
    unsigned short* xb = (unsigned short*)d_ws;
    unsigned short* wb = xb + (size_t)M * K;

    {
        int nthread = (int)(((size_t)M * K) / 8);
        xcv_kernel<<<nthread / 256, 256, 0, stream>>>(x, xb);
    }
    {
        int nthread = (int)(((size_t)N * K) / 8);
        wdq_kernel<<<nthread / 256, 256, 0, stream>>>(w_codes, am_codes, am_scale, am_off, wb);
    }
    {
        dim3 grid(N / BLK_N, M / BLK_M);
        gemm_bt<<<grid, 256, 0, stream>>>(xb, wb, bias, out, M, N, K);
    }
}

// Round 2
// 610.139 us; speedup vs baseline: 1.0049x; 1.0049x over previous
//
#include <hip/hip_runtime.h>
#include <cstdint>
#include <cstddef>

// Problem dims (fixed by setup_inputs): B=4, S=2048, I=4096, O=4096
#define DIM_M 8192   // B*S
#define DIM_N 4096   // O
#define DIM_K 4096   // I

#define BLK_M 128
#define BLK_N 128
#define BLK_K 32

typedef __bf16 bf16x8 __attribute__((ext_vector_type(8)));
typedef float floatx4 __attribute__((ext_vector_type(4)));

__device__ __constant__ float NF4_TAB[16] = {
    -1.0f, -0.6961928009986877f, -0.5250730514526367f, -0.39491748809814453f,
    -0.28444138169288635f, -0.18477343022823334f, -0.09105003625154495f, 0.0f,
    0.07958029955625534f, 0.16093020141124725f, 0.24611230194568634f,
    0.33791524171829224f, 0.44070982933044434f, 0.5626170039176941f,
    0.7229568362236023f, 1.0f};

// float -> bf16 bits, round-to-nearest-even (finite inputs only)
__device__ inline unsigned short f2bf(float f) {
    unsigned int u = __builtin_bit_cast(unsigned int, f);
    u += 0x7fffu + ((u >> 16) & 1u);
    return (unsigned short)(u >> 16);
}

// ---------------- fused prep: x fp32->bf16  +  NF4 double-dequant ----------------
// blockIdx.x < xcv_blocks : convert x (8 elems/thread)
// else                    : dequant w  (8 elems/thread)
__global__ void prep_kernel(const float* __restrict__ x, unsigned short* __restrict__ xb,
                            const int* __restrict__ codes,
                            const int* __restrict__ am_codes,
                            const float* __restrict__ am_scale,
                            const float* __restrict__ am_off,
                            unsigned short* __restrict__ wb,
                            int xcv_blocks) {
    if ((int)blockIdx.x < xcv_blocks) {
        size_t base = ((size_t)blockIdx.x * blockDim.x + threadIdx.x) * 8;
        float4 a = *(const float4*)(x + base);
        float4 b = *(const float4*)(x + base + 4);
        unsigned short r[8];
        r[0] = f2bf(a.x); r[1] = f2bf(a.y); r[2] = f2bf(a.z); r[3] = f2bf(a.w);
        r[4] = f2bf(b.x); r[5] = f2bf(b.y); r[6] = f2bf(b.z); r[7] = f2bf(b.w);
        *(uint4*)(xb + base) = *(const uint4*)r;
    } else {
        __shared__ float nf4[16];
        if (threadIdx.x < 16) nf4[threadIdx.x] = NF4_TAB[threadIdx.x];
        __syncthreads();
        size_t base = ((size_t)(blockIdx.x - xcv_blocks) * blockDim.x + threadIdx.x) * 8;
        int blk = (int)(base >> 6);
        float absmax = (float)am_codes[blk] * (1.0f / 255.0f) * am_scale[blk >> 8] + am_off[0];
        int4 c0 = *(const int4*)(codes + base);
        int4 c1 = *(const int4*)(codes + base + 4);
        unsigned short r[8];
        r[0] = f2bf(nf4[c0.x & 15] * absmax);
        r[1] = f2bf(nf4[c0.y & 15] * absmax);
        r[2] = f2bf(nf4[c0.z & 15] * absmax);
        r[3] = f2bf(nf4[c0.w & 15] * absmax);
        r[4] = f2bf(nf4[c1.x & 15] * absmax);
        r[5] = f2bf(nf4[c1.y & 15] * absmax);
        r[6] = f2bf(nf4[c1.z & 15] * absmax);
        r[7] = f2bf(nf4[c1.w & 15] * absmax);
        *(uint4*)(wb + base) = *(const uint4*)r;
    }
}

// ---------------- bf16 MFMA GEMM, B^T input, bias epilogue ----------------
// LDS layout is XOR-swizzled to kill ds_read_b128 bank conflicts:
// LDS slot (row, chunk c) holds global chunk (row, c ^ ((row>>1)&3)),
// where a chunk is 8 bf16 = 16 B (4 chunks per 32-elem row).
// Staging keeps the mandatory contiguous lane->LDS mapping (base + lane*16)
// and permutes each lane's *global source* chunk instead.
__device__ inline void gld_lds16(const void* g, void* l) {
    __builtin_amdgcn_global_load_lds((__attribute__((address_space(1))) void*)g,
                                     (__attribute__((address_space(3))) void*)l,
                                     16, 0, 0);
}

__global__ __launch_bounds__(256) void gemm_bt(const unsigned short* __restrict__ A,
                                               const unsigned short* __restrict__ B,
                                               const float* __restrict__ bias,
                                               float* __restrict__ C,
                                               int M, int N, int K) {
    __shared__ __attribute__((aligned(16))) unsigned short lA[BLK_M * BLK_K];
    __shared__ __attribute__((aligned(16))) unsigned short lB[BLK_N * BLK_K];
    const int tid = threadIdx.x;
    const int wave = tid >> 6;
    const int lane = tid & 63;
    const int bm = blockIdx.y, bn = blockIdx.x;

    const int wm = (wave >> 1) * 64;  // wave m-offset within tile
    const int wn = (wave & 1) * 64;   // wave n-offset within tile

    // Staging: thread t owns LDS slots (row = t>>2, c = t&3) and (row+64, c).
    // Swizzle s(row) = (row>>1)&3; both slots share s = (t>>3)&3.
    // Global chunk column to fetch: cg = (t&3) ^ s.
    const int er0 = tid >> 2;                       // row 0..63
    const int cg  = (tid & 3) ^ ((tid >> 3) & 3);   // swizzled source chunk
    const unsigned short* gA = A + (size_t)(bm * BLK_M + er0) * K + cg * 8;
    const unsigned short* gB = B + (size_t)(bn * BLK_N + er0) * K + cg * 8;
    unsigned short* lA0 = &lA[tid * 8];
    unsigned short* lA1 = &lA[2048 + tid * 8];  // rows 64..127
    unsigned short* lB0 = &lB[tid * 8];
    unsigned short* lB1 = &lB[2048 + tid * 8];
    const size_t rstride = (size_t)64 * K;

    floatx4 acc[4][4];
#pragma unroll
    for (int i = 0; i < 4; ++i)
#pragma unroll
        for (int j = 0; j < 4; ++j)
#pragma unroll
            for (int r = 0; r < 4; ++r) acc[i][j][r] = 0.0f;

    // MFMA 16x16x32 A-operand layout: lane holds A[m = lane&15][k = (lane>>4)*8 + j]
    // Fragment row R = wm + i*16 + mrow; since wm and i*16 are multiples of 16,
    // (R>>1)&3 == (mrow>>1)&3 -> swizzled chunk offset is lane-constant.
    const int mrow = lane & 15;
    const int co = (((lane >> 4) ^ ((mrow >> 1) & 3)) * 8);  // swizzled k-offset

    for (int k0 = 0; k0 < K; k0 += BLK_K) {
        gld_lds16(gA, lA0);
        gld_lds16(gA + rstride, lA1);
        gld_lds16(gB, lB0);
        gld_lds16(gB + rstride, lB1);
        gA += BLK_K;
        gB += BLK_K;
        __syncthreads();  // drains vmcnt -> staging visible

        bf16x8 af[4], bfr[4];
#pragma unroll
        for (int i = 0; i < 4; ++i) {
            af[i] = *(const bf16x8*)&lA[(wm + i * 16 + mrow) * BLK_K + co];
            bfr[i] = *(const bf16x8*)&lB[(wn + i * 16 + mrow) * BLK_K + co];
        }
#pragma unroll
        for (int i = 0; i < 4; ++i)
#pragma unroll
            for (int j = 0; j < 4; ++j)
                acc[i][j] = __builtin_amdgcn_mfma_f32_16x16x32_bf16(af[i], bfr[j], acc[i][j], 0, 0, 0);
        __syncthreads();  // compute done before next stage overwrites
    }

    // Epilogue. C/D layout: col = lane&15, row = (lane>>4)*4 + reg
    const int r0 = (lane >> 4) * 4;
    const int col = lane & 15;
#pragma unroll
    for (int j = 0; j < 4; ++j) {
        int gn = bn * BLK_N + wn + j * 16 + col;
        float bv = bias[gn];
#pragma unroll
        for (int i = 0; i < 4; ++i) {
            int gm = bm * BLK_M + wm + i * 16 + r0;
            float* cp = C + (size_t)gm * N + gn;
            cp[0]              = acc[i][j][0] + bv;
            cp[(size_t)N]      = acc[i][j][1] + bv;
            cp[2 * (size_t)N]  = acc[i][j][2] + bv;
            cp[3 * (size_t)N]  = acc[i][j][3] + bv;
        }
    }
}

extern "C" void kernel_launch(void* const* d_in, const int* in_sizes, int n_in,
                              void* d_out, int out_size, void* d_ws, size_t ws_size,
                              hipStream_t stream) {
    const float* x        = (const float*)d_in[0];
    const int*   w_codes  = (const int*)d_in[1];
    const int*   am_codes = (const int*)d_in[2];
    const float* am_scale = (const float*)d_in[3];
    const float* am_off   = (const float*)d_in[4];
    const float* bias     = (const float*)d_in[5];
    float* out = (float*)d_out;

    const int M = DIM_M, N = DIM_N, K = DIM_K;

    // workspace: xb (M*K bf16 = 64 MB) | wb (N*K bf16 = 32 MB)
    unsigned short* xb = (unsigned short*)d_ws;
    unsigned short* wb = xb + (size_t)M * K;

    {
        int xcv_blocks = (int)(((size_t)M * K) / 8 / 256);   // 16384
        int wdq_blocks = (int)(((size_t)N * K) / 8 / 256);   // 8192
        prep_kernel<<<xcv_blocks + wdq_blocks, 256, 0, stream>>>(
            x, xb, w_codes, am_codes, am_scale, am_off, wb, xcv_blocks);
    }
    {
        dim3 grid(N / BLK_N, M / BLK_M);
        gemm_bt<<<grid, 256, 0, stream>>>(xb, wb, bias, out, M, N, K);
    }
}

// Round 4
// 572.872 us; speedup vs baseline: 1.0703x; 1.0651x over previous
//
#include <hip/hip_runtime.h>
#include <cstdint>
#include <cstddef>

// Problem dims (fixed by setup_inputs): B=4, S=2048, I=4096, O=4096
#define DIM_M 8192   // B*S
#define DIM_N 4096   // O
#define DIM_K 4096   // I

#define BLK_M 128
#define BLK_N 128
#define BLK_K 32

typedef __bf16 bf16x8 __attribute__((ext_vector_type(8)));
typedef float floatx16 __attribute__((ext_vector_type(16)));
typedef float fvec4 __attribute__((ext_vector_type(4)));   // nontemporal-compatible
typedef int   ivec4 __attribute__((ext_vector_type(4)));
typedef unsigned int uvec4 __attribute__((ext_vector_type(4)));

__device__ __constant__ float NF4_TAB[16] = {
    -1.0f, -0.6961928009986877f, -0.5250730514526367f, -0.39491748809814453f,
    -0.28444138169288635f, -0.18477343022823334f, -0.09105003625154495f, 0.0f,
    0.07958029955625534f, 0.16093020141124725f, 0.24611230194568634f,
    0.33791524171829224f, 0.44070982933044434f, 0.5626170039176941f,
    0.7229568362236023f, 1.0f};

// float -> bf16 bits, round-to-nearest-even (finite inputs only)
__device__ inline unsigned short f2bf(float f) {
    unsigned int u = __builtin_bit_cast(unsigned int, f);
    u += 0x7fffu + ((u >> 16) & 1u);
    return (unsigned short)(u >> 16);
}

// ---------------- fused prep: x fp32->bf16  +  NF4 double-dequant ----------------
// Nontemporal loads: x and codes are read-once streams — don't pollute L2/L3
// (xb/wb writes stay cacheable; the GEMM reads them next).
__global__ void prep_kernel(const float* __restrict__ x, unsigned short* __restrict__ xb,
                            const int* __restrict__ codes,
                            const int* __restrict__ am_codes,
                            const float* __restrict__ am_scale,
                            const float* __restrict__ am_off,
                            unsigned short* __restrict__ wb,
                            int xcv_blocks) {
    if ((int)blockIdx.x < xcv_blocks) {
        size_t base = ((size_t)blockIdx.x * blockDim.x + threadIdx.x) * 8;
        fvec4 a = __builtin_nontemporal_load((const fvec4*)(x + base));
        fvec4 b = __builtin_nontemporal_load((const fvec4*)(x + base + 4));
        unsigned short r[8];
        r[0] = f2bf(a.x); r[1] = f2bf(a.y); r[2] = f2bf(a.z); r[3] = f2bf(a.w);
        r[4] = f2bf(b.x); r[5] = f2bf(b.y); r[6] = f2bf(b.z); r[7] = f2bf(b.w);
        *(uvec4*)(xb + base) = *(const uvec4*)r;
    } else {
        __shared__ float nf4[16];
        if (threadIdx.x < 16) nf4[threadIdx.x] = NF4_TAB[threadIdx.x];
        __syncthreads();
        size_t base = ((size_t)(blockIdx.x - xcv_blocks) * blockDim.x + threadIdx.x) * 8;
        int blk = (int)(base >> 6);
        float absmax = (float)am_codes[blk] * (1.0f / 255.0f) * am_scale[blk >> 8] + am_off[0];
        ivec4 c0 = __builtin_nontemporal_load((const ivec4*)(codes + base));
        ivec4 c1 = __builtin_nontemporal_load((const ivec4*)(codes + base + 4));
        unsigned short r[8];
        r[0] = f2bf(nf4[c0.x & 15] * absmax);
        r[1] = f2bf(nf4[c0.y & 15] * absmax);
        r[2] = f2bf(nf4[c0.z & 15] * absmax);
        r[3] = f2bf(nf4[c0.w & 15] * absmax);
        r[4] = f2bf(nf4[c1.x & 15] * absmax);
        r[5] = f2bf(nf4[c1.y & 15] * absmax);
        r[6] = f2bf(nf4[c1.z & 15] * absmax);
        r[7] = f2bf(nf4[c1.w & 15] * absmax);
        *(uvec4*)(wb + base) = *(const uvec4*)r;
    }
}

// ---------------- bf16 MFMA GEMM (32x32x16), B^T input, bias epilogue ----------------
// LDS XOR-swizzle: slot (row, chunk c) holds global chunk (row, c ^ ((row>>1)&3)),
// chunk = 8 bf16 = 16 B. Staging keeps the mandatory contiguous lane->LDS mapping
// (base + lane*16) and permutes each lane's *global source* chunk instead.
// Read side (32x32 frags): every 8 consecutive lanes cover all 32 banks once ->
// conflict-free at the b128 128B/clk ceiling.
__device__ inline void gld_lds16(const void* g, void* l) {
    __builtin_amdgcn_global_load_lds((__attribute__((address_space(1))) void*)g,
                                     (__attribute__((address_space(3))) void*)l,
                                     16, 0, 0);
}

__global__ __launch_bounds__(256) void gemm_bt(const unsigned short* __restrict__ A,
                                               const unsigned short* __restrict__ B,
                                               const float* __restrict__ bias,
                                               float* __restrict__ C,
                                               int M, int N, int K) {
    __shared__ __attribute__((aligned(16))) unsigned short lA[BLK_M * BLK_K];
    __shared__ __attribute__((aligned(16))) unsigned short lB[BLK_N * BLK_K];
    const int tid = threadIdx.x;
    const int wave = tid >> 6;
    const int lane = tid & 63;

    // XCD/L2-aware remap: linear l -> (bm, bn) such that same-XCD blocks
    // (stride 8 in dispatch order) share an A-tile row, and all XCDs walk
    // the same bn sequence in lockstep (B-tiles L3-hot).
    // l = g*256 + bnv*8 + r  ->  bm = g*8 + r, bn = bnv   (bijective)
    const int l = blockIdx.y * gridDim.x + blockIdx.x;
    const int bn = (l >> 3) & 31;
    const int bm = ((l >> 8) << 3) + (l & 7);

    const int wm = (wave >> 1) * 64;  // wave m-offset within tile
    const int wn = (wave & 1) * 64;   // wave n-offset within tile

    // Staging: thread t owns LDS slots (row = t>>2, c = t&3) and (row+64, c).
    // Swizzle s(row) = (row>>1)&3; both slots share s = (t>>3)&3.
    const int er0 = tid >> 2;                       // row 0..63
    const int cg  = (tid & 3) ^ ((tid >> 3) & 3);   // swizzled source chunk
    const unsigned short* gA = A + (size_t)(bm * BLK_M + er0) * K + cg * 8;
    const unsigned short* gB = B + (size_t)(bn * BLK_N + er0) * K + cg * 8;
    unsigned short* lA0 = &lA[tid * 8];
    unsigned short* lA1 = &lA[2048 + tid * 8];  // rows 64..127
    unsigned short* lB0 = &lB[tid * 8];
    unsigned short* lB1 = &lB[2048 + tid * 8];
    const size_t rstride = (size_t)64 * K;

    floatx16 acc[2][2];
#pragma unroll
    for (int i = 0; i < 2; ++i)
#pragma unroll
        for (int j = 0; j < 2; ++j)
#pragma unroll
            for (int r = 0; r < 16; ++r) acc[i][j][r] = 0.0f;

    // MFMA 32x32x16 A/B-operand layout: lane holds X[mn = lane&31][k = (lane>>5)*8 + j]
    // Fragment row R = w? + i*32 + arow; w? and 32i are multiples of 8 -> swizzle
    // term depends only on arow.
    const int arow = lane & 31;
    const int half = lane >> 5;
    const int swz = (arow >> 1) & 3;

    for (int k0 = 0; k0 < K; k0 += BLK_K) {
        gld_lds16(gA, lA0);
        gld_lds16(gA + rstride, lA1);
        gld_lds16(gB, lB0);
        gld_lds16(gB + rstride, lB1);
        gA += BLK_K;
        gB += BLK_K;
        __syncthreads();  // drains vmcnt -> staging visible

        bf16x8 af[2][2], bfr[2][2];  // [tile][k-step]
#pragma unroll
        for (int s = 0; s < 2; ++s) {
            const int co = (((s << 1) + half) ^ swz) * 8;  // swizzled k-chunk offset
#pragma unroll
            for (int i = 0; i < 2; ++i) {
                af[i][s]  = *(const bf16x8*)&lA[(wm + i * 32 + arow) * BLK_K + co];
                bfr[i][s] = *(const bf16x8*)&lB[(wn + i * 32 + arow) * BLK_K + co];
            }
        }
#pragma unroll
        for (int s = 0; s < 2; ++s)
#pragma unroll
            for (int i = 0; i < 2; ++i)
#pragma unroll
                for (int j = 0; j < 2; ++j)
                    acc[i][j] = __builtin_amdgcn_mfma_f32_32x32x16_bf16(af[i][s], bfr[j][s], acc[i][j], 0, 0, 0);
        __syncthreads();  // compute done before next stage overwrites
    }

    // Epilogue. 32x32 C/D layout: col = lane&31, row = (reg&3) + 8*(reg>>2) + 4*(lane>>5)
    // C is write-once -> nontemporal stores (don't evict wb/xb from L2/L3).
#pragma unroll
    for (int j = 0; j < 2; ++j) {
        int gn = bn * BLK_N + wn + j * 32 + arow;
        float bv = bias[gn];
#pragma unroll
        for (int i = 0; i < 2; ++i) {
            int gm0 = bm * BLK_M + wm + i * 32 + half * 4;
#pragma unroll
            for (int r = 0; r < 16; ++r) {
                int row = (r & 3) + ((r >> 2) << 3);
                __builtin_nontemporal_store(acc[i][j][r] + bv,
                                            C + (size_t)(gm0 + row) * N + gn);
            }
        }
    }
}

extern "C" void kernel_launch(void* const* d_in, const int* in_sizes, int n_in,
                              void* d_out, int out_size, void* d_ws, size_t ws_size,
                              hipStream_t stream) {
    const float* x        = (const float*)d_in[0];
    const int*   w_codes  = (const int*)d_in[1];
    const int*   am_codes = (const int*)d_in[2];
    const float* am_scale = (const float*)d_in[3];
    const float* am_off   = (const float*)d_in[4];
    const float* bias     = (const float*)d_in[5];
    float* out = (float*)d_out;

    const int M = DIM_M, N = DIM_N, K = DIM_K;

    // workspace: xb (M*K bf16 = 64 MB) | wb (N*K bf16 = 32 MB)
    unsigned short* xb = (unsigned short*)d_ws;
    unsigned short* wb = xb + (size_t)M * K;

    {
        int xcv_blocks = (int)(((size_t)M * K) / 8 / 256);   // 16384
        int wdq_blocks = (int)(((size_t)N * K) / 8 / 256);   // 8192
        prep_kernel<<<xcv_blocks + wdq_blocks, 256, 0, stream>>>(
            x, xb, w_codes, am_codes, am_scale, am_off, wb, xcv_blocks);
    }
    {
        dim3 grid(N / BLK_N, M / BLK_M);
        gemm_bt<<<grid, 256, 0, stream>>>(xb, wb, bias, out, M, N, K);
    }
}